// Round 6
// baseline (528.818 us; speedup 1.0000x reference)
//
#include <hip/hip_runtime.h>
#include <hip/hip_bf16.h>

#define BF __hip_bfloat16

// B=16, C=64, H=128, W=128, MX=MY=24, HIDDEN=32
// RESOLVED (R5 forensics): inputs fp32, OUTPUT fp32 (reference dtypes, per
// harness doc). R2/R3/R5's identical 6.597656 = packed-bf16 output read as
// fp32; R1/R4 NaN = fp32 input decoded as bf16. This round: fp32 in/out.
//
// Intermediates bf16 (spectral branch magnitude ~5e-4; 0.4% relative bf16
// noise -> ~2e-6 absolute on the output, threshold is 0.1269).
//
// Workspace (bf16 units, peak 7471104 units = 14.94 MB):
//   Tr [0,3145728)        [bc][y24][u128]   (dead after k_fft_h)
//   Ti [3145728,6291456)
//   Xr [6291456,6881280)  [xy][bc]          (dead after k_mix)
//   Xi [6881280,7471104)
//   Sr [0,589824)         [bo][xy]   aliases Tr (T dead)
//   Si [589824,1179648)
//   Pr [1179648,4325376)  [bo][u][y] aliases Tr/Ti tail (dead)
//   Pi [4325376,7471104)             aliases Ti/X (X dead after k_mix)

__device__ __forceinline__ float geluf(float v) {
    return 0.5f * v * (1.0f + erff(v * 0.7071067811865476f));
}
__device__ __forceinline__ float bf2f(BF v) { return __bfloat162float(v); }

// ---------------------------------------------------------------------------
// k_fft_w: forward DFT along W.  T[bc][y][u] = sum_v x[bc][u][v] e^{-2pi i v y/128}
// Block = (bc, half of rows).  Grid 2048.
// ---------------------------------------------------------------------------
__global__ __launch_bounds__(256) void k_fft_w(const float* __restrict__ x,
                                               BF* __restrict__ TrB,
                                               BF* __restrict__ TiB) {
    __shared__ __align__(16) float xs[64 * 132];
    __shared__ __align__(16) float tcs[24 * 132];
    __shared__ __align__(16) float tss[24 * 132];
    const int tid = threadIdx.x;
    const int bc  = blockIdx.x >> 1;
    const int uh  = (blockIdx.x & 1) << 6;            // 0 or 64

    for (int i = tid; i < 3072; i += 256) {
        int m = i >> 7, a = i & 127;
        int r = (a * m) & 127;
        float th = (float)r * 0.04908738521234052f;   // 2*pi/128
        float s, c; __sincosf(th, &s, &c);
        tcs[m * 132 + a] = c;
        tss[m * 132 + a] = s;
    }
    const float4* xb = (const float4*)(x + ((size_t)bc << 14) + ((size_t)uh << 7));
    for (int i = tid; i < 2048; i += 256) {           // 64 rows * 32 float4
        float4 v = xb[i];
        int row = i >> 5, col = (i & 31) << 2;
        *(float4*)&xs[row * 132 + col] = v;
    }
    __syncthreads();

    if (tid < 192) {
        const int ut = tid / 12, yt = tid - ut * 12;  // 16 u-tiles x 12 y-tiles
        const int u0 = ut << 2, y0 = yt << 1;         // 4u x 2y register tile
        float ar[4][2] = {}, ai[4][2] = {};
        for (int v = 0; v < 128; v += 4) {
            float4 xv[4], c4[2], s4[2];
            #pragma unroll
            for (int i = 0; i < 4; ++i) xv[i] = *(const float4*)&xs[(u0 + i) * 132 + v];
            #pragma unroll
            for (int j = 0; j < 2; ++j) {
                c4[j] = *(const float4*)&tcs[(y0 + j) * 132 + v];
                s4[j] = *(const float4*)&tss[(y0 + j) * 132 + v];
            }
            #pragma unroll
            for (int i = 0; i < 4; ++i)
                #pragma unroll
                for (int j = 0; j < 2; ++j) {
                    ar[i][j] += xv[i].x * c4[j].x + xv[i].y * c4[j].y
                              + xv[i].z * c4[j].z + xv[i].w * c4[j].w;
                    ai[i][j] -= xv[i].x * s4[j].x + xv[i].y * s4[j].y
                              + xv[i].z * s4[j].z + xv[i].w * s4[j].w;
                }
        }
        const size_t tb = (size_t)bc * 3072 + uh + u0;
        #pragma unroll
        for (int j = 0; j < 2; ++j)
            #pragma unroll
            for (int i = 0; i < 4; ++i) {
                TrB[tb + (size_t)(y0 + j) * 128 + i] = __float2bfloat16(ar[i][j]);
                TiB[tb + (size_t)(y0 + j) * 128 + i] = __float2bfloat16(ai[i][j]);
            }
    }
}

// ---------------------------------------------------------------------------
// k_fft_h: forward DFT along H.  X[x,y] = sum_u T[y][u] e^{-2pi i u x/128}
// Block = bc.  X layout [x*24+y][bc].
// ---------------------------------------------------------------------------
__global__ __launch_bounds__(256) void k_fft_h(const BF* __restrict__ TrB,
                                               const BF* __restrict__ TiB,
                                               BF* __restrict__ XrB,
                                               BF* __restrict__ XiB) {
    __shared__ __align__(16) float tcs[24 * 132], tss[24 * 132];
    __shared__ __align__(16) float Trs[24 * 132], Tis[24 * 132];
    const int tid = threadIdx.x;
    const int bc  = blockIdx.x;

    for (int i = tid; i < 3072; i += 256) {
        int m = i >> 7, a = i & 127;
        int r = (a * m) & 127;
        float th = (float)r * 0.04908738521234052f;
        float s, c; __sincosf(th, &s, &c);
        tcs[m * 132 + a] = c;
        tss[m * 132 + a] = s;
    }
    for (int i = tid; i < 3072; i += 256) {
        int y = i >> 7, u = i & 127;
        Trs[y * 132 + u] = bf2f(TrB[(size_t)bc * 3072 + i]);
        Tis[y * 132 + u] = bf2f(TiB[(size_t)bc * 3072 + i]);
    }
    __syncthreads();

    if (tid < 144) {
        const int xt = tid / 12, yt = tid - xt * 12;
        const int x0 = xt << 1, y0 = yt << 1;
        float zr[2][2] = {}, zi[2][2] = {};
        for (int u = 0; u < 128; u += 4) {
            float4 t4[2], q4[2], c4[2], s4[2];
            #pragma unroll
            for (int j = 0; j < 2; ++j) {
                t4[j] = *(const float4*)&Trs[(y0 + j) * 132 + u];
                q4[j] = *(const float4*)&Tis[(y0 + j) * 132 + u];
            }
            #pragma unroll
            for (int i = 0; i < 2; ++i) {
                c4[i] = *(const float4*)&tcs[(x0 + i) * 132 + u];
                s4[i] = *(const float4*)&tss[(x0 + i) * 132 + u];
            }
            #pragma unroll
            for (int i = 0; i < 2; ++i)
                #pragma unroll
                for (int j = 0; j < 2; ++j) {
                    zr[i][j] += t4[j].x * c4[i].x + q4[j].x * s4[i].x
                              + t4[j].y * c4[i].y + q4[j].y * s4[i].y
                              + t4[j].z * c4[i].z + q4[j].z * s4[i].z
                              + t4[j].w * c4[i].w + q4[j].w * s4[i].w;
                    zi[i][j] += q4[j].x * c4[i].x - t4[j].x * s4[i].x
                              + q4[j].y * c4[i].y - t4[j].y * s4[i].y
                              + q4[j].z * c4[i].z - t4[j].z * s4[i].z
                              + q4[j].w * c4[i].w - t4[j].w * s4[i].w;
                }
        }
        #pragma unroll
        for (int i = 0; i < 2; ++i)
            #pragma unroll
            for (int j = 0; j < 2; ++j) {
                int xy = (x0 + i) * 24 + (y0 + j);
                XrB[(size_t)xy * 1024 + bc] = __float2bfloat16(zr[i][j]);
                XiB[(size_t)xy * 1024 + bc] = __float2bfloat16(zi[i][j]);
            }
    }
}

// ---------------------------------------------------------------------------
// k_mix: per-mode complex channel mix.  S[b,o] = sum_c X[b,c] * (wr + i wi)[c,o]
// Block = xy (576).  Weights fp32 direct.  S layout [b*64+o][xy].
// ---------------------------------------------------------------------------
__global__ __launch_bounds__(256) void k_mix(const float* __restrict__ wr_g,
                                             const float* __restrict__ wi_g,
                                             const BF* __restrict__ XrB,
                                             const BF* __restrict__ XiB,
                                             BF* __restrict__ SrB,
                                             BF* __restrict__ SiB) {
    __shared__ __align__(16) float Wr[4096], Wi[4096];   // [c][o]
    __shared__ __align__(16) float Xr[16 * 68], Xi[16 * 68];
    const int tid = threadIdx.x;
    const int xy  = blockIdx.x;

    const float4* wr4 = (const float4*)(wr_g + ((size_t)xy << 12));
    const float4* wi4 = (const float4*)(wi_g + ((size_t)xy << 12));
    for (int i = tid; i < 1024; i += 256) {
        *(float4*)&Wr[i << 2] = wr4[i];
        *(float4*)&Wi[i << 2] = wi4[i];
    }
    for (int i = tid; i < 1024; i += 256) {
        int b = i >> 6, c = i & 63;
        Xr[b * 68 + c] = bf2f(XrB[((size_t)xy << 10) + i]);
        Xi[b * 68 + c] = bf2f(XiB[((size_t)xy << 10) + i]);
    }
    __syncthreads();

    const int b  = tid >> 4;
    const int o0 = (tid & 15) << 2;
    float4 sr = {0.f, 0.f, 0.f, 0.f}, si = {0.f, 0.f, 0.f, 0.f};
    const float* xrp = Xr + b * 68;
    const float* xip = Xi + b * 68;
    for (int c = 0; c < 64; ++c) {
        float ar = xrp[c], ac = xip[c];
        float4 w_r = *(const float4*)&Wr[(c << 6) + o0];
        float4 w_i = *(const float4*)&Wi[(c << 6) + o0];
        sr.x += ar * w_r.x - ac * w_i.x;  si.x += ar * w_i.x + ac * w_r.x;
        sr.y += ar * w_r.y - ac * w_i.y;  si.y += ar * w_i.y + ac * w_r.y;
        sr.z += ar * w_r.z - ac * w_i.z;  si.z += ar * w_i.z + ac * w_r.z;
        sr.w += ar * w_r.w - ac * w_i.w;  si.w += ar * w_i.w + ac * w_r.w;
    }
    size_t base = (size_t)((b << 6) + o0) * 576 + xy;
    SrB[base]        = __float2bfloat16(sr.x);  SiB[base]        = __float2bfloat16(si.x);
    SrB[base + 576]  = __float2bfloat16(sr.y);  SiB[base + 576]  = __float2bfloat16(si.y);
    SrB[base + 1152] = __float2bfloat16(sr.z);  SiB[base + 1152] = __float2bfloat16(si.z);
    SrB[base + 1728] = __float2bfloat16(sr.w);  SiB[base + 1728] = __float2bfloat16(si.w);
}

// ---------------------------------------------------------------------------
// k_invP: inverse H-transform.  P[u,y] = sum_x S[x,y] e^{+2pi i u x/128},
// folding hermitian weight (y=0: x1, Im:=0; y>0: x2) and the 1/16384 norm.
// Block = bo (1024).  P layout [bo][u][y].
// ---------------------------------------------------------------------------
__global__ __launch_bounds__(256) void k_invP(const BF* __restrict__ SrB,
                                              const BF* __restrict__ SiB,
                                              BF* __restrict__ PrB,
                                              BF* __restrict__ PiB) {
    __shared__ __align__(16) float Srs[24 * 28], Sis[24 * 28];   // [y][x]
    __shared__ __align__(16) float tcs[24 * 132], tss[24 * 132]; // [m][a]
    const int tid = threadIdx.x;
    const int bo  = blockIdx.x;

    for (int i = tid; i < 3072; i += 256) {
        int m = i >> 7, a = i & 127;
        int r = (a * m) & 127;
        float th = (float)r * 0.04908738521234052f;
        float s, c; __sincosf(th, &s, &c);
        tcs[m * 132 + a] = c;
        tss[m * 132 + a] = s;
    }
    for (int i = tid; i < 576; i += 256) {
        int xx = i / 24, yy = i - xx * 24;
        Srs[yy * 28 + xx] = bf2f(SrB[(size_t)bo * 576 + i]);
        Sis[yy * 28 + xx] = bf2f(SiB[(size_t)bo * 576 + i]);
    }
    __syncthreads();

    const int u  = tid & 127;
    const int yh = (tid >> 7) * 12;
    float tcu[24], tsu[24];
    #pragma unroll
    for (int xx = 0; xx < 24; ++xx) {
        tcu[xx] = tcs[xx * 132 + u];
        tsu[xx] = tss[xx * 132 + u];
    }
    const float inv = 6.103515625e-05f;   // 1/16384
    BF* prp = PrB + (size_t)bo * 3072 + (size_t)u * 24;
    BF* pip = PiB + (size_t)bo * 3072 + (size_t)u * 24;
    for (int jy = 0; jy < 12; ++jy) {
        int y = yh + jy;
        float pr = 0.f, pi = 0.f;
        #pragma unroll
        for (int xq = 0; xq < 6; ++xq) {
            int x0 = xq << 2;
            float4 s4 = *(const float4*)&Srs[y * 28 + x0];
            float4 z4 = *(const float4*)&Sis[y * 28 + x0];
            pr += s4.x * tcu[x0]     - z4.x * tsu[x0]
                + s4.y * tcu[x0 + 1] - z4.y * tsu[x0 + 1]
                + s4.z * tcu[x0 + 2] - z4.z * tsu[x0 + 2]
                + s4.w * tcu[x0 + 3] - z4.w * tsu[x0 + 3];
            pi += z4.x * tcu[x0]     + s4.x * tsu[x0]
                + z4.y * tcu[x0 + 1] + s4.y * tsu[x0 + 1]
                + z4.z * tcu[x0 + 2] + s4.z * tsu[x0 + 2]
                + z4.w * tcu[x0 + 3] + s4.w * tsu[x0 + 3];
        }
        if (y == 0) {
            prp[0] = __float2bfloat16(pr * inv);
            pip[0] = __float2bfloat16(0.f);
        } else {
            prp[y] = __float2bfloat16(2.f * inv * pr);
            pip[y] = __float2bfloat16(2.f * inv * pi);
        }
    }
}

// ---------------------------------------------------------------------------
// k_fused: inverse W-transform (spec) + skip + GELU + MLP + soft-gate.
// Block = (b, u): 2048 blocks, 128 threads (= v).
// Phase 1: 64o x 128v spec GEMM over 24 y (8x8 register tiles).
// Phase 2: per-pixel epilogue; fp32 x loads, fp32 out stores.
// ---------------------------------------------------------------------------
__global__ __launch_bounds__(128) void k_fused(const float* __restrict__ x,
                                               const BF* __restrict__ PrB,
                                               const BF* __restrict__ PiB,
                                               const float* __restrict__ wsk,
                                               const float* __restrict__ w1,
                                               const float* __restrict__ b1,
                                               const float* __restrict__ w2,
                                               const float* __restrict__ b2,
                                               const float* __restrict__ gt,
                                               float* __restrict__ out) {
    __shared__ __align__(16) float buf[9536];
    float* tcv = buf;            // 3168 = 24*132
    float* tsv = buf + 3168;     // 3168
    float* Pp  = buf + 6336;     // 3200 = 64*50  [o][2y], pad 50
    float* spc = buf;            // 8192 = 64*128, aliases tw/Pp after GEMM

    const int tid = threadIdx.x;
    const int b = blockIdx.x >> 7;
    const int u = blockIdx.x & 127;

    for (int i = tid; i < 3072; i += 128) {
        int m = i >> 7, a = i & 127;
        int r = (a * m) & 127;
        float th = (float)r * 0.04908738521234052f;
        float s, c; __sincosf(th, &s, &c);
        tcv[m * 132 + a] = c;
        tsv[m * 132 + a] = s;
    }
    const size_t pb = (size_t)(b * 64) * 3072 + (size_t)u * 24;
    for (int i = tid; i < 1536; i += 128) {
        int o = i / 24, y = i - o * 24;
        Pp[o * 50 + 2 * y]     = bf2f(PrB[pb + (size_t)o * 3072 + y]);
        Pp[o * 50 + 2 * y + 1] = bf2f(PiB[pb + (size_t)o * 3072 + y]);
    }
    __syncthreads();

    {   // spec GEMM: thread = (og, vg) -> 8 o x 8 v tile
        const int o0 = (tid >> 4) << 3;
        const int v0 = (tid & 15) << 3;
        float acc[8][8];
        #pragma unroll
        for (int i = 0; i < 8; ++i)
            #pragma unroll
            for (int j = 0; j < 8; ++j) acc[i][j] = 0.f;
        for (int y = 0; y < 24; ++y) {
            float4 c0 = *(const float4*)&tcv[y * 132 + v0];
            float4 c1 = *(const float4*)&tcv[y * 132 + v0 + 4];
            float4 s0 = *(const float4*)&tsv[y * 132 + v0];
            float4 s1 = *(const float4*)&tsv[y * 132 + v0 + 4];
            float cj[8] = {c0.x, c0.y, c0.z, c0.w, c1.x, c1.y, c1.z, c1.w};
            float sj[8] = {s0.x, s0.y, s0.z, s0.w, s1.x, s1.y, s1.z, s1.w};
            #pragma unroll
            for (int i = 0; i < 8; ++i) {
                float2 A = *(const float2*)&Pp[(o0 + i) * 50 + 2 * y];
                #pragma unroll
                for (int j = 0; j < 8; ++j)
                    acc[i][j] += A.x * cj[j] - A.y * sj[j];
            }
        }
        __syncthreads();   // all tw/Pp reads done before spc overwrites
        #pragma unroll
        for (int i = 0; i < 8; ++i) {
            *(float4*)&spc[(o0 + i) * 128 + v0] =
                make_float4(acc[i][0], acc[i][1], acc[i][2], acc[i][3]);
            *(float4*)&spc[(o0 + i) * 128 + v0 + 4] =
                make_float4(acc[i][4], acc[i][5], acc[i][6], acc[i][7]);
        }
    }
    __syncthreads();

    // epilogue: thread = v
    const int v = tid;
    const float* xb = x + ((size_t)(b * 64) * 128 + u) * 128 + v;
    float xv[64];
    #pragma unroll
    for (int c = 0; c < 64; ++c) xv[c] = xb[(size_t)c * 16384];

    float h1[64];
    #pragma unroll
    for (int o = 0; o < 64; ++o) {
        float a = spc[o * 128 + v];
        #pragma unroll
        for (int c = 0; c < 64; ++c) a += xv[c] * wsk[(o << 6) + c];
        h1[o] = geluf(a);
    }
    float z1[32];
    #pragma unroll
    for (int k = 0; k < 32; ++k) {
        float a = b1[k];
        #pragma unroll
        for (int c = 0; c < 64; ++c) a += h1[c] * w1[(k << 6) + c];
        z1[k] = geluf(a);
    }
    float* ob = out + ((size_t)(b * 64) * 128 + u) * 128 + v;
    #pragma unroll
    for (int o = 0; o < 64; ++o) {
        float a = b2[o];
        #pragma unroll
        for (int k = 0; k < 32; ++k) a += z1[k] * w2[(o << 5) + k];
        a += gt[o] * h1[o];
        ob[(size_t)o * 16384] = a;
    }
}

// ---------------------------------------------------------------------------
extern "C" void kernel_launch(void* const* d_in, const int* in_sizes, int n_in,
                              void* d_out, int out_size, void* d_ws, size_t ws_size,
                              hipStream_t stream) {
    (void)in_sizes; (void)n_in; (void)out_size; (void)ws_size;
    const float* x   = (const float*)d_in[0];
    const float* wr  = (const float*)d_in[1];
    const float* wi  = (const float*)d_in[2];
    const float* wsk = (const float*)d_in[3];
    const float* w1  = (const float*)d_in[4];
    const float* b1  = (const float*)d_in[5];
    const float* w2  = (const float*)d_in[6];
    const float* b2  = (const float*)d_in[7];
    const float* gt  = (const float*)d_in[8];

    BF* wsB = (BF*)d_ws;
    BF* Tr  = wsB;                 // [0, 3145728)
    BF* Ti  = wsB + 3145728;       // [3145728, 6291456)
    BF* Xr  = wsB + 6291456;       // [6291456, 6881280)
    BF* Xi  = wsB + 6881280;       // [6881280, 7471104)
    BF* Sr  = wsB;                 // aliases Tr (T dead after k_fft_h)
    BF* Si  = wsB + 589824;
    BF* Pr  = wsB + 1179648;       // [1179648, 4325376) aliases Tr/Ti (dead)
    BF* Pi  = wsB + 4325376;       // [4325376, 7471104) aliases Ti/X (X dead)
    // peak footprint: 7471104 bf16 = 14.94 MB

    hipLaunchKernelGGL(k_fft_w, dim3(2048), dim3(256), 0, stream, x, Tr, Ti);
    hipLaunchKernelGGL(k_fft_h, dim3(1024), dim3(256), 0, stream, Tr, Ti, Xr, Xi);
    hipLaunchKernelGGL(k_mix,   dim3(576),  dim3(256), 0, stream, wr, wi, Xr, Xi, Sr, Si);
    hipLaunchKernelGGL(k_invP,  dim3(1024), dim3(256), 0, stream, Sr, Si, Pr, Pi);
    hipLaunchKernelGGL(k_fused, dim3(2048), dim3(128), 0, stream,
                       x, Pr, Pi, wsk, w1, b1, w2, b2, gt, (float*)d_out);
}